// Round 1
// baseline (635.059 us; speedup 1.0000x reference)
//
#include <hip/hip_runtime.h>

#define NN 50000
#define EE 800000
#define HH 128
#define CC 10
#define GG 128

// ---------------- CSR build ----------------

__global__ void count_kernel(const int* __restrict__ dst, int* cnt) {
    int e = blockIdx.x * 256 + threadIdx.x;
    if (e < EE) atomicAdd(&cnt[dst[e]], 1);
}

__global__ void scan1_kernel(const int* cnt, int* bsum) {
    __shared__ int s[512];
    int n = blockIdx.x * 512 + threadIdx.x;
    s[threadIdx.x] = (n < NN) ? cnt[n] : 0;
    __syncthreads();
    for (int off = 256; off > 0; off >>= 1) {
        if (threadIdx.x < off) s[threadIdx.x] += s[threadIdx.x + off];
        __syncthreads();
    }
    if (threadIdx.x == 0) bsum[blockIdx.x] = s[0];
}

__global__ void scan2_kernel(int* bsum, int* rowptr, int nb) {
    __shared__ int s[128];
    int t = threadIdx.x;
    int v = (t < nb) ? bsum[t] : 0;
    s[t] = v;
    __syncthreads();
    for (int off = 1; off < 128; off <<= 1) {
        int tt = (t >= off) ? s[t - off] : 0;
        __syncthreads();
        s[t] += tt;
        __syncthreads();
    }
    if (t < nb) bsum[t] = s[t] - v;   // exclusive block offsets
    if (t == 0) rowptr[NN] = EE;
}

__global__ void scan3_kernel(const int* cnt, const int* bsum, int* rowptr, int* cursor) {
    __shared__ int s[512];
    int t = threadIdx.x;
    int n = blockIdx.x * 512 + t;
    int v = (n < NN) ? cnt[n] : 0;
    s[t] = v;
    __syncthreads();
    for (int off = 1; off < 512; off <<= 1) {
        int tt = (t >= off) ? s[t - off] : 0;
        __syncthreads();
        s[t] += tt;
        __syncthreads();
    }
    int excl = s[t] - v + bsum[blockIdx.x];
    if (n < NN) { rowptr[n] = excl; cursor[n] = excl; }
}

__global__ void fill_kernel(const int* __restrict__ src, const int* __restrict__ dst,
                            int* cursor, int* eidx) {
    int e = blockIdx.x * 256 + threadIdx.x;
    if (e < EE) {
        int p = atomicAdd(&cursor[dst[e]], 1);
        eidx[p] = src[e];
    }
}

// ---------------- aggregation: one wave per destination node ----------------

__global__ __launch_bounds__(256) void aggregate_kernel(const float* __restrict__ h,
                                                        const int* __restrict__ rowptr,
                                                        const int* __restrict__ eidx,
                                                        float* __restrict__ agg) {
    int node = blockIdx.x * 4 + (threadIdx.x >> 6);
    if (node >= NN) return;
    int lane = threadIdx.x & 63;
    int beg = rowptr[node], end = rowptr[node + 1];
    float2 acc = make_float2(0.f, 0.f);
    for (int i = beg; i < end; ++i) {
        int sidx = eidx[i];
        float2 v = ((const float2*)(h + (size_t)sidx * HH))[lane];
        acc.x += v.x;
        acc.y += v.y;
    }
    ((float2*)(agg + (size_t)node * HH))[lane] = acc;
}

// ---------------- fp32 GEMM: Y = relu(X @ W + b), X = eps1*h + agg if COMBINE ----------------
// block: 64 rows x 128 cols, 512 threads, 4x4 register tile per thread.
// W staged in k-chunks of 64 (32KB LDS), X chunk 64x64 padded to stride 68.

template <bool COMBINE>
__global__ __launch_bounds__(512) void mlp_gemm(const float* __restrict__ xin,
                                                const float* agg,
                                                const float* __restrict__ W,
                                                const float* __restrict__ bias,
                                                const float* __restrict__ epsp, int layer,
                                                float* out, int nrows) {
    __shared__ float ws[64 * HH];   // 32 KB
    __shared__ float xs[64 * 68];   // ~17 KB, padded stride
    const int tid = threadIdx.x;
    const int tx = tid & 31, ty = tid >> 5;
    const int j0 = tx * 4, r0 = ty * 4;
    const int row0 = blockIdx.x * 64;
    float eps1 = 1.0f;
    if (COMBINE) eps1 = 1.0f + epsp[layer];

    float acc[4][4];
#pragma unroll
    for (int i = 0; i < 4; ++i)
#pragma unroll
        for (int j = 0; j < 4; ++j) acc[i][j] = 0.f;

    for (int kc = 0; kc < 2; ++kc) {
        if (kc) __syncthreads();
        // stage W chunk: 64 x 128 floats = 2048 float4
#pragma unroll
        for (int it = 0; it < 4; ++it) {
            int idx = it * 512 + tid;
            int kk = idx >> 5, jq = idx & 31;
            float4 wv = *(const float4*)(W + (size_t)(kc * 64 + kk) * HH + jq * 4);
            *(float4*)&ws[kk * HH + jq * 4] = wv;
        }
        // stage X chunk: 64 rows x 64 k = 1024 float4
#pragma unroll
        for (int it = 0; it < 2; ++it) {
            int idx = it * 512 + tid;
            int r = idx >> 4, kq = idx & 15;
            int row = row0 + r;
            float4 xv = make_float4(0.f, 0.f, 0.f, 0.f);
            if (row < nrows) {
                const float* p = xin + (size_t)row * HH + kc * 64 + kq * 4;
                xv = *(const float4*)p;
                if (COMBINE) {
                    const float* q = agg + (size_t)row * HH + kc * 64 + kq * 4;
                    float4 av = *(const float4*)q;
                    xv.x = eps1 * xv.x + av.x;
                    xv.y = eps1 * xv.y + av.y;
                    xv.z = eps1 * xv.z + av.z;
                    xv.w = eps1 * xv.w + av.w;
                }
            }
            *(float4*)&xs[r * 68 + kq * 4] = xv;
        }
        __syncthreads();
        // compute 64 k-steps
#pragma unroll
        for (int k = 0; k < 64; k += 4) {
            float4 xr[4];
#pragma unroll
            for (int i = 0; i < 4; ++i) xr[i] = *(const float4*)&xs[(r0 + i) * 68 + k];
#pragma unroll
            for (int kk = 0; kk < 4; ++kk) {
                float4 wv = *(const float4*)&ws[(k + kk) * HH + j0];
#pragma unroll
                for (int i = 0; i < 4; ++i) {
                    float xv = (kk == 0) ? xr[i].x : (kk == 1) ? xr[i].y : (kk == 2) ? xr[i].z : xr[i].w;
                    acc[i][0] += xv * wv.x;
                    acc[i][1] += xv * wv.y;
                    acc[i][2] += xv * wv.z;
                    acc[i][3] += xv * wv.w;
                }
            }
        }
    }
    float4 bv = *(const float4*)(bias + j0);
#pragma unroll
    for (int i = 0; i < 4; ++i) {
        int row = row0 + r0 + i;
        if (row < nrows) {
            float4 o;
            o.x = fmaxf(acc[i][0] + bv.x, 0.f);
            o.y = fmaxf(acc[i][1] + bv.y, 0.f);
            o.z = fmaxf(acc[i][2] + bv.z, 0.f);
            o.w = fmaxf(acc[i][3] + bv.w, 0.f);
            *(float4*)(out + (size_t)row * HH + j0) = o;
        }
    }
}

// ---------------- sum pooling (graph_ids sorted -> register accumulate, flush on change) ----------------

__global__ __launch_bounds__(128) void pool_kernel(const float* __restrict__ h,
                                                   const int* __restrict__ gid,
                                                   float* hg) {
    int j = threadIdx.x;
    int n0 = blockIdx.x * 256;
    int nend = (n0 + 256 < NN) ? n0 + 256 : NN;
    int gcur = -1;
    float acc = 0.f;
    for (int n = n0; n < nend; ++n) {
        int g = gid[n];
        if (g != gcur) {
            if (gcur >= 0) atomicAdd(&hg[gcur * HH + j], acc);
            gcur = g;
            acc = 0.f;
        }
        acc += h[(size_t)n * HH + j];
    }
    if (gcur >= 0) atomicAdd(&hg[gcur * HH + j], acc);
}

// ---------------- classifier head ----------------

__global__ __launch_bounds__(128) void classify_kernel(const float* __restrict__ hg,
                                                       const float* __restrict__ wc1,
                                                       const float* __restrict__ bc1,
                                                       const float* __restrict__ wc2,
                                                       const float* __restrict__ bc2,
                                                       float* __restrict__ out) {
    __shared__ float xrow[HH];
    __shared__ float trow[HH];
    int g = blockIdx.x, j = threadIdx.x;
    xrow[j] = hg[g * HH + j];
    __syncthreads();
    float s = bc1[j];
    for (int k = 0; k < HH; ++k) s += xrow[k] * wc1[k * HH + j];
    trow[j] = fmaxf(s, 0.f);
    __syncthreads();
    if (j < CC) {
        float o = bc2[j];
        for (int k = 0; k < HH; ++k) o += trow[k] * wc2[k * CC + j];
        out[g * CC + j] = o;
    }
}

extern "C" void kernel_launch(void* const* d_in, const int* in_sizes, int n_in,
                              void* d_out, int out_size, void* d_ws, size_t ws_size,
                              hipStream_t stream) {
    const float* features = (const float*)d_in[0];
    const int* src = (const int*)d_in[1];
    const int* dst = (const int*)d_in[2];
    const int* gid = (const int*)d_in[3];
    const float* eps = (const float*)d_in[4];
    const float* w1[3] = {(const float*)d_in[5], (const float*)d_in[9], (const float*)d_in[13]};
    const float* b1[3] = {(const float*)d_in[6], (const float*)d_in[10], (const float*)d_in[14]};
    const float* w2[3] = {(const float*)d_in[7], (const float*)d_in[11], (const float*)d_in[15]};
    const float* b2[3] = {(const float*)d_in[8], (const float*)d_in[12], (const float*)d_in[16]};
    const float* wc1 = (const float*)d_in[17];
    const float* bc1 = (const float*)d_in[18];
    const float* wc2 = (const float*)d_in[19];
    const float* bc2 = (const float*)d_in[20];
    float* outp = (float*)d_out;

    char* ws = (char*)d_ws;
    size_t off = 0;
    auto alloc = [&](size_t bytes) {
        void* p = ws + off;
        off += (bytes + 255) & ~(size_t)255;
        return p;
    };
    int* rowptr = (int*)alloc((NN + 1) * sizeof(int));
    int* cursor = (int*)alloc(NN * sizeof(int));
    int* eidx = (int*)alloc(EE * sizeof(int));
    int* bsum = (int*)alloc(128 * sizeof(int));
    float* hbuf = (float*)alloc((size_t)NN * HH * sizeof(float));
    float* aggbuf = (float*)alloc((size_t)NN * HH * sizeof(float));
    float* hg = (float*)alloc(GG * HH * sizeof(float));

    const int NB = (NN + 511) / 512;  // 98

    // CSR build (per call; src/dst constant so reused across the 3 layers)
    hipMemsetAsync(cursor, 0, NN * sizeof(int), stream);
    count_kernel<<<(EE + 255) / 256, 256, 0, stream>>>(dst, cursor);
    scan1_kernel<<<NB, 512, 0, stream>>>(cursor, bsum);
    scan2_kernel<<<1, 128, 0, stream>>>(bsum, rowptr, NB);
    scan3_kernel<<<NB, 512, 0, stream>>>(cursor, bsum, rowptr, cursor);
    fill_kernel<<<(EE + 255) / 256, 256, 0, stream>>>(src, dst, cursor, eidx);

    // 3 GIN layers
    const float* hin = features;
    for (int i = 0; i < 3; ++i) {
        aggregate_kernel<<<(NN + 3) / 4, 256, 0, stream>>>(hin, rowptr, eidx, aggbuf);
        // tmp = relu((1+eps)*h + agg) @ w1 + b1)   (written in-place into aggbuf)
        mlp_gemm<true><<<(NN + 63) / 64, 512, 0, stream>>>(hin, aggbuf, w1[i], b1[i], eps, i, aggbuf, NN);
        // h = relu(tmp @ w2 + b2)
        mlp_gemm<false><<<(NN + 63) / 64, 512, 0, stream>>>(aggbuf, nullptr, w2[i], b2[i], eps, i, hbuf, NN);
        hin = hbuf;
    }

    // pooling + classifier
    hipMemsetAsync(hg, 0, GG * HH * sizeof(float), stream);
    pool_kernel<<<(NN + 255) / 256, 128, 0, stream>>>(hbuf, gid, hg);
    classify_kernel<<<GG, 128, 0, stream>>>(hg, wc1, bc1, wc2, bc2, outp);
}

// Round 2
// 411.319 us; speedup vs baseline: 1.5440x; 1.5440x over previous
//
#include <hip/hip_runtime.h>

#define NN 50000
#define EE 800000
#define HH 128
#define CC 10
#define GG 128

typedef __attribute__((ext_vector_type(8))) short short8;
typedef __attribute__((ext_vector_type(4))) float f32x4;

// ---------- bf16 helpers (RNE) ----------
__device__ __forceinline__ ushort f2b(float f) {
    union { float f; uint u; } x; x.f = f;
    uint u = x.u;
    uint r = (u + 0x7fffu + ((u >> 16) & 1u)) >> 16;
    return (ushort)r;
}
__device__ __forceinline__ float lo2f(uint v) {
    union { uint u; float f; } x; x.u = v << 16; return x.f;
}
__device__ __forceinline__ float hi2f(uint v) {
    union { uint u; float f; } x; x.u = v & 0xffff0000u; return x.f;
}
__device__ __forceinline__ float b2f(ushort v) {
    union { uint u; float f; } x; x.u = ((uint)v) << 16; return x.f;
}
__device__ __forceinline__ uint comb2(uint hv, uint av, float e) {
    float fl = e * lo2f(hv) + lo2f(av);
    float fh = e * hi2f(hv) + hi2f(av);
    return (uint)f2b(fl) | (((uint)f2b(fh)) << 16);
}

// ---------------- CSR build ----------------

__global__ void count_kernel(const int* __restrict__ dst, int* cnt) {
    int e = blockIdx.x * 256 + threadIdx.x;
    if (e < EE) atomicAdd(&cnt[dst[e]], 1);
}

__global__ void scan1_kernel(const int* cnt, int* bsum) {
    __shared__ int s[512];
    int n = blockIdx.x * 512 + threadIdx.x;
    s[threadIdx.x] = (n < NN) ? cnt[n] : 0;
    __syncthreads();
    for (int off = 256; off > 0; off >>= 1) {
        if (threadIdx.x < off) s[threadIdx.x] += s[threadIdx.x + off];
        __syncthreads();
    }
    if (threadIdx.x == 0) bsum[blockIdx.x] = s[0];
}

__global__ void scan2_kernel(int* bsum, int* rowptr, int nb) {
    __shared__ int s[128];
    int t = threadIdx.x;
    int v = (t < nb) ? bsum[t] : 0;
    s[t] = v;
    __syncthreads();
    for (int off = 1; off < 128; off <<= 1) {
        int tt = (t >= off) ? s[t - off] : 0;
        __syncthreads();
        s[t] += tt;
        __syncthreads();
    }
    if (t < nb) bsum[t] = s[t] - v;   // exclusive block offsets
    if (t == 0) rowptr[NN] = EE;
}

__global__ void scan3_kernel(const int* cnt, const int* bsum, int* rowptr, int* cursor) {
    __shared__ int s[512];
    int t = threadIdx.x;
    int n = blockIdx.x * 512 + t;
    int v = (n < NN) ? cnt[n] : 0;
    s[t] = v;
    __syncthreads();
    for (int off = 1; off < 512; off <<= 1) {
        int tt = (t >= off) ? s[t - off] : 0;
        __syncthreads();
        s[t] += tt;
        __syncthreads();
    }
    int excl = s[t] - v + bsum[blockIdx.x];
    if (n < NN) { rowptr[n] = excl; cursor[n] = excl; }
}

__global__ void fill_kernel(const int* __restrict__ src, const int* __restrict__ dst,
                            int* cursor, int* eidx) {
    int e = blockIdx.x * 256 + threadIdx.x;
    if (e < EE) {
        int p = atomicAdd(&cursor[dst[e]], 1);
        eidx[p] = src[e];
    }
}

// ---------------- conversions ----------------

__global__ __launch_bounds__(256) void f2b_kernel(const float* __restrict__ in,
                                                  ushort* __restrict__ out, int n4) {
    int i = blockIdx.x * 256 + threadIdx.x;
    if (i < n4) {
        float4 v = ((const float4*)in)[i];
        ushort4 o;
        o.x = f2b(v.x); o.y = f2b(v.y); o.z = f2b(v.z); o.w = f2b(v.w);
        ((ushort4*)out)[i] = o;
    }
}

// transpose-convert the 6 MLP weights: wt[mi][n][k] = bf16(w_mi[k][n])
__global__ __launch_bounds__(256) void wconv_kernel(const float* w0, const float* w1,
                                                    const float* w2, const float* w3,
                                                    const float* w4, const float* w5,
                                                    ushort* __restrict__ wt) {
    const float* src;
    switch (blockIdx.y) {
        case 0: src = w0; break; case 1: src = w1; break;
        case 2: src = w2; break; case 3: src = w3; break;
        case 4: src = w4; break; default: src = w5; break;
    }
    int idx = blockIdx.x * 256 + threadIdx.x;   // 0..16383
    int n = idx >> 7, k = idx & 127;
    wt[blockIdx.y * 16384 + n * 128 + k] = f2b(src[k * 128 + n]);
}

// ---------------- aggregation: one wave per destination node (bf16) ----------------

__global__ __launch_bounds__(256) void aggregate_kernel(const ushort* __restrict__ h,
                                                        const int* __restrict__ rowptr,
                                                        const int* __restrict__ eidx,
                                                        ushort* __restrict__ agg) {
    int node = blockIdx.x * 4 + (threadIdx.x >> 6);
    if (node >= NN) return;
    int lane = threadIdx.x & 63;
    int beg = rowptr[node], end = rowptr[node + 1];
    float ax = 0.f, ay = 0.f;
    int i = beg;
    for (; i + 1 < end; i += 2) {
        int s0 = eidx[i], s1 = eidx[i + 1];
        uint v0 = *(const uint*)(h + (size_t)s0 * HH + lane * 2);
        uint v1 = *(const uint*)(h + (size_t)s1 * HH + lane * 2);
        ax += lo2f(v0); ay += hi2f(v0);
        ax += lo2f(v1); ay += hi2f(v1);
    }
    if (i < end) {
        int s0 = eidx[i];
        uint v0 = *(const uint*)(h + (size_t)s0 * HH + lane * 2);
        ax += lo2f(v0); ay += hi2f(v0);
    }
    uint o = (uint)f2b(ax) | (((uint)f2b(ay)) << 16);
    *(uint*)(agg + (size_t)node * HH + lane * 2) = o;
}

// ---------------- MFMA GEMM: out = relu(X @ W + b), X = (1+eps)*h + agg if COMBINE -----
// D = Wt_frag (A, rows=n) x X_frag (B, cols=m): D[n][m] = sum_k W[k][n] X[m][k] = out[m][n].
// C/D layout: m = lane&15, n = (lane>>4)*4 + reg  ->  lane packs 4 consecutive out cols -> 8B store.
// Block: 64 rows(m) x 128 cols(n), 256 threads (4 waves); wave w owns n in [w*32, w*32+32).

template <bool COMBINE>
__global__ __launch_bounds__(256) void mfma_gemm(const ushort* __restrict__ xin,
                                                 const ushort* __restrict__ agg,
                                                 const ushort* __restrict__ wt,   // [n][k] bf16
                                                 const float* __restrict__ bias,
                                                 const float* __restrict__ epsp, int layer,
                                                 ushort* __restrict__ out, int nrows) {
    __shared__ __align__(16) ushort xs[64][136];   // padded: 2-way-bank-free ds_read_b128
    const int tid = threadIdx.x;
    const int lane = tid & 63, w = tid >> 6;
    const int row0 = blockIdx.x * 64;
    const int l15 = lane & 15, lhi = lane >> 4;

    // preload all A (Wt) fragments from global (L2-resident, 32KB total)
    short8 af[2][4];
#pragma unroll
    for (int fa = 0; fa < 2; ++fa)
#pragma unroll
        for (int kt = 0; kt < 4; ++kt) {
            int n = w * 32 + fa * 16 + l15;
            int k = kt * 32 + lhi * 8;
            af[fa][kt] = *(const short8*)(wt + n * HH + k);
        }

    // stage X tile (combine with agg for layer input)
    float eps1 = 1.0f;
    if (COMBINE) eps1 = 1.0f + epsp[layer];
#pragma unroll
    for (int it = 0; it < 4; ++it) {
        int idx = it * 256 + tid;
        int r = idx >> 4, kq = idx & 15;
        int row = row0 + r;
        uint4 xv = make_uint4(0u, 0u, 0u, 0u);
        if (row < nrows) {
            xv = *(const uint4*)(xin + (size_t)row * HH + kq * 8);
            if (COMBINE) {
                uint4 av = *(const uint4*)(agg + (size_t)row * HH + kq * 8);
                xv.x = comb2(xv.x, av.x, eps1);
                xv.y = comb2(xv.y, av.y, eps1);
                xv.z = comb2(xv.z, av.z, eps1);
                xv.w = comb2(xv.w, av.w, eps1);
            }
        }
        *(uint4*)&xs[r][kq * 8] = xv;
    }
    __syncthreads();

    f32x4 acc[2][4];
#pragma unroll
    for (int fa = 0; fa < 2; ++fa)
#pragma unroll
        for (int fb = 0; fb < 4; ++fb) acc[fa][fb] = (f32x4)(0.f);

#pragma unroll
    for (int kt = 0; kt < 4; ++kt) {
        short8 bfr[4];
#pragma unroll
        for (int fb = 0; fb < 4; ++fb)
            bfr[fb] = *(const short8*)&xs[fb * 16 + l15][kt * 32 + lhi * 8];
#pragma unroll
        for (int fa = 0; fa < 2; ++fa)
#pragma unroll
            for (int fb = 0; fb < 4; ++fb)
                acc[fa][fb] = __builtin_amdgcn_mfma_f32_16x16x32_bf16(af[fa][kt], bfr[fb],
                                                                     acc[fa][fb], 0, 0, 0);
    }

    // epilogue: bias + relu + bf16 pack (4 consecutive cols per lane -> 8B store)
#pragma unroll
    for (int fa = 0; fa < 2; ++fa) {
        int nb = w * 32 + fa * 16 + lhi * 4;
        float4 bv = *(const float4*)(bias + nb);
#pragma unroll
        for (int fb = 0; fb < 4; ++fb) {
            int m = row0 + fb * 16 + l15;
            if (m < nrows) {
                ushort4 o;
                o.x = f2b(fmaxf(acc[fa][fb][0] + bv.x, 0.f));
                o.y = f2b(fmaxf(acc[fa][fb][1] + bv.y, 0.f));
                o.z = f2b(fmaxf(acc[fa][fb][2] + bv.z, 0.f));
                o.w = f2b(fmaxf(acc[fa][fb][3] + bv.w, 0.f));
                *(ushort4*)(out + (size_t)m * HH + nb) = o;
            }
        }
    }
}

// ---------------- sum pooling (bf16 in, fp32 accumulate) ----------------

__global__ __launch_bounds__(128) void pool_kernel(const ushort* __restrict__ h,
                                                   const int* __restrict__ gid,
                                                   float* hg) {
    int j = threadIdx.x;
    int n0 = blockIdx.x * 256;
    int nend = (n0 + 256 < NN) ? n0 + 256 : NN;
    int gcur = -1;
    float acc = 0.f;
    for (int n = n0; n < nend; ++n) {
        int g = gid[n];
        if (g != gcur) {
            if (gcur >= 0) atomicAdd(&hg[gcur * HH + j], acc);
            gcur = g;
            acc = 0.f;
        }
        acc += b2f(h[(size_t)n * HH + j]);
    }
    if (gcur >= 0) atomicAdd(&hg[gcur * HH + j], acc);
}

// ---------------- classifier head (fp32) ----------------

__global__ __launch_bounds__(128) void classify_kernel(const float* __restrict__ hg,
                                                       const float* __restrict__ wc1,
                                                       const float* __restrict__ bc1,
                                                       const float* __restrict__ wc2,
                                                       const float* __restrict__ bc2,
                                                       float* __restrict__ out) {
    __shared__ float xrow[HH];
    __shared__ float trow[HH];
    int g = blockIdx.x, j = threadIdx.x;
    xrow[j] = hg[g * HH + j];
    __syncthreads();
    float s = bc1[j];
    for (int k = 0; k < HH; ++k) s += xrow[k] * wc1[k * HH + j];
    trow[j] = fmaxf(s, 0.f);
    __syncthreads();
    if (j < CC) {
        float o = bc2[j];
        for (int k = 0; k < HH; ++k) o += trow[k] * wc2[k * CC + j];
        out[g * CC + j] = o;
    }
}

extern "C" void kernel_launch(void* const* d_in, const int* in_sizes, int n_in,
                              void* d_out, int out_size, void* d_ws, size_t ws_size,
                              hipStream_t stream) {
    const float* features = (const float*)d_in[0];
    const int* src = (const int*)d_in[1];
    const int* dst = (const int*)d_in[2];
    const int* gid = (const int*)d_in[3];
    const float* eps = (const float*)d_in[4];
    const float* w1[3] = {(const float*)d_in[5], (const float*)d_in[9], (const float*)d_in[13]};
    const float* b1[3] = {(const float*)d_in[6], (const float*)d_in[10], (const float*)d_in[14]};
    const float* w2[3] = {(const float*)d_in[7], (const float*)d_in[11], (const float*)d_in[15]};
    const float* b2[3] = {(const float*)d_in[8], (const float*)d_in[12], (const float*)d_in[16]};
    const float* wc1 = (const float*)d_in[17];
    const float* bc1 = (const float*)d_in[18];
    const float* wc2 = (const float*)d_in[19];
    const float* bc2 = (const float*)d_in[20];
    float* outp = (float*)d_out;

    char* ws = (char*)d_ws;
    size_t off = 0;
    auto alloc = [&](size_t bytes) {
        void* p = ws + off;
        off += (bytes + 255) & ~(size_t)255;
        return p;
    };
    int* rowptr = (int*)alloc((NN + 1) * sizeof(int));
    int* cursor = (int*)alloc(NN * sizeof(int));
    int* eidx = (int*)alloc(EE * sizeof(int));
    int* bsum = (int*)alloc(128 * sizeof(int));
    ushort* hb0 = (ushort*)alloc((size_t)NN * HH * 2);    // features bf16
    ushort* hb1 = (ushort*)alloc((size_t)NN * HH * 2);    // layer h bf16
    ushort* tb = (ushort*)alloc((size_t)NN * HH * 2);     // mlp hidden bf16
    ushort* aggb = (ushort*)alloc((size_t)NN * HH * 2);   // aggregate bf16
    ushort* wtb = (ushort*)alloc(6 * 16384 * 2);          // transposed bf16 weights
    float* hg = (float*)alloc(GG * HH * sizeof(float));

    const int NB = (NN + 511) / 512;  // 98

    // CSR build
    hipMemsetAsync(cursor, 0, NN * sizeof(int), stream);
    count_kernel<<<(EE + 255) / 256, 256, 0, stream>>>(dst, cursor);
    scan1_kernel<<<NB, 512, 0, stream>>>(cursor, bsum);
    scan2_kernel<<<1, 128, 0, stream>>>(bsum, rowptr, NB);
    scan3_kernel<<<NB, 512, 0, stream>>>(cursor, bsum, rowptr, cursor);
    fill_kernel<<<(EE + 255) / 256, 256, 0, stream>>>(src, dst, cursor, eidx);

    // conversions
    f2b_kernel<<<(NN * HH / 4 + 255) / 256, 256, 0, stream>>>(features, hb0, NN * HH / 4);
    dim3 wg(64, 6);
    wconv_kernel<<<wg, 256, 0, stream>>>(w1[0], w2[0], w1[1], w2[1], w1[2], w2[2], wtb);
    // wtb layout: [0]=w1_0, [1]=w2_0, [2]=w1_1, [3]=w2_1, [4]=w1_2, [5]=w2_2

    const int GB = (NN + 63) / 64;  // 782

    // 3 GIN layers
    const ushort* hin = hb0;
    for (int i = 0; i < 3; ++i) {
        aggregate_kernel<<<(NN + 3) / 4, 256, 0, stream>>>(hin, rowptr, eidx, aggb);
        mfma_gemm<true><<<GB, 256, 0, stream>>>(hin, aggb, wtb + (2 * i) * 16384,
                                                b1[i], eps, i, tb, NN);
        mfma_gemm<false><<<GB, 256, 0, stream>>>(tb, nullptr, wtb + (2 * i + 1) * 16384,
                                                 b2[i], eps, i, hb1, NN);
        hin = hb1;
    }

    // pooling + classifier
    hipMemsetAsync(hg, 0, GG * HH * sizeof(float), stream);
    pool_kernel<<<(NN + 255) / 256, 128, 0, stream>>>(hb1, gid, hg);
    classify_kernel<<<GG, 128, 0, stream>>>(hg, wc1, bc1, wc2, bc2, outp);
}

// Round 3
// 297.839 us; speedup vs baseline: 2.1322x; 1.3810x over previous
//
#include <hip/hip_runtime.h>

#define NN 50000
#define EE 800000
#define HH 128
#define CC 10
#define GG 128

typedef __attribute__((ext_vector_type(8))) short short8;
typedef __attribute__((ext_vector_type(4))) float f32x4;

// ---------- bf16 helpers (RNE) ----------
__device__ __forceinline__ ushort f2b(float f) {
    union { float f; uint u; } x; x.f = f;
    uint u = x.u;
    uint r = (u + 0x7fffu + ((u >> 16) & 1u)) >> 16;
    return (ushort)r;
}
__device__ __forceinline__ float lo2f(uint v) {
    union { uint u; float f; } x; x.u = v << 16; return x.f;
}
__device__ __forceinline__ float hi2f(uint v) {
    union { uint u; float f; } x; x.u = v & 0xffff0000u; return x.f;
}
__device__ __forceinline__ uint comb2(uint hv, uint av, float e) {
    float fl = e * lo2f(hv) + lo2f(av);
    float fh = e * hi2f(hv) + hi2f(av);
    return (uint)f2b(fl) | (((uint)f2b(fh)) << 16);
}

// ---------------- CSR build ----------------

__global__ void count_kernel(const int* __restrict__ dst, int* cnt) {
    int e = blockIdx.x * 256 + threadIdx.x;
    if (e < EE) atomicAdd(&cnt[dst[e]], 1);
}

__global__ void scan1_kernel(const int* cnt, int* bsum) {
    __shared__ int s[512];
    int n = blockIdx.x * 512 + threadIdx.x;
    s[threadIdx.x] = (n < NN) ? cnt[n] : 0;
    __syncthreads();
    for (int off = 256; off > 0; off >>= 1) {
        if (threadIdx.x < off) s[threadIdx.x] += s[threadIdx.x + off];
        __syncthreads();
    }
    if (threadIdx.x == 0) bsum[blockIdx.x] = s[0];
}

__global__ void scan2_kernel(int* bsum, int* rowptr, int nb) {
    __shared__ int s[128];
    int t = threadIdx.x;
    int v = (t < nb) ? bsum[t] : 0;
    s[t] = v;
    __syncthreads();
    for (int off = 1; off < 128; off <<= 1) {
        int tt = (t >= off) ? s[t - off] : 0;
        __syncthreads();
        s[t] += tt;
        __syncthreads();
    }
    if (t < nb) bsum[t] = s[t] - v;   // exclusive block offsets
    if (t == 0) rowptr[NN] = EE;
}

__global__ void scan3_kernel(const int* cnt, const int* bsum, int* rowptr, int* cursor) {
    __shared__ int s[512];
    int t = threadIdx.x;
    int n = blockIdx.x * 512 + t;
    int v = (n < NN) ? cnt[n] : 0;
    s[t] = v;
    __syncthreads();
    for (int off = 1; off < 512; off <<= 1) {
        int tt = (t >= off) ? s[t - off] : 0;
        __syncthreads();
        s[t] += tt;
        __syncthreads();
    }
    int excl = s[t] - v + bsum[blockIdx.x];
    if (n < NN) { rowptr[n] = excl; cursor[n] = excl; }
}

__global__ void fill_kernel(const int* __restrict__ src, const int* __restrict__ dst,
                            int* cursor, int* eidx) {
    int e = blockIdx.x * 256 + threadIdx.x;
    if (e < EE) {
        int p = atomicAdd(&cursor[dst[e]], 1);
        eidx[p] = src[e];
    }
}

// ---------------- conversions ----------------

__global__ __launch_bounds__(256) void f2b_kernel(const float* __restrict__ in,
                                                  ushort* __restrict__ out, int n4) {
    int i = blockIdx.x * 256 + threadIdx.x;
    if (i < n4) {
        float4 v = ((const float4*)in)[i];
        ushort4 o;
        o.x = f2b(v.x); o.y = f2b(v.y); o.z = f2b(v.z); o.w = f2b(v.w);
        ((ushort4*)out)[i] = o;
    }
}

// transpose-convert the 6 MLP weights: wt[mi][n][k] = bf16(w_mi[k][n])
__global__ __launch_bounds__(256) void wconv_kernel(const float* w0, const float* w1,
                                                    const float* w2, const float* w3,
                                                    const float* w4, const float* w5,
                                                    ushort* __restrict__ wt) {
    const float* src;
    switch (blockIdx.y) {
        case 0: src = w0; break; case 1: src = w1; break;
        case 2: src = w2; break; case 3: src = w3; break;
        case 4: src = w4; break; default: src = w5; break;
    }
    int idx = blockIdx.x * 256 + threadIdx.x;   // 0..16383
    int n = idx >> 7, k = idx & 127;
    wt[blockIdx.y * 16384 + n * 128 + k] = f2b(src[k * 128 + n]);
}

// ---------------- aggregation: one wave per destination node (bf16, 4x unroll) ------

__global__ __launch_bounds__(256) void aggregate_kernel(const ushort* __restrict__ h,
                                                        const int* __restrict__ rowptr,
                                                        const int* __restrict__ eidx,
                                                        ushort* __restrict__ agg) {
    int node = blockIdx.x * 4 + (threadIdx.x >> 6);
    if (node >= NN) return;
    int lane = threadIdx.x & 63;
    int beg = rowptr[node], end = rowptr[node + 1];
    float ax = 0.f, ay = 0.f;
    int i = beg;
    for (; i + 4 <= end; i += 4) {
        int s0 = eidx[i], s1 = eidx[i + 1], s2 = eidx[i + 2], s3 = eidx[i + 3];
        uint v0 = *(const uint*)(h + (size_t)s0 * HH + lane * 2);
        uint v1 = *(const uint*)(h + (size_t)s1 * HH + lane * 2);
        uint v2 = *(const uint*)(h + (size_t)s2 * HH + lane * 2);
        uint v3 = *(const uint*)(h + (size_t)s3 * HH + lane * 2);
        ax += lo2f(v0) + lo2f(v1) + lo2f(v2) + lo2f(v3);
        ay += hi2f(v0) + hi2f(v1) + hi2f(v2) + hi2f(v3);
    }
    for (; i < end; ++i) {
        int s0 = eidx[i];
        uint v0 = *(const uint*)(h + (size_t)s0 * HH + lane * 2);
        ax += lo2f(v0); ay += hi2f(v0);
    }
    uint o = (uint)f2b(ax) | (((uint)f2b(ay)) << 16);
    *(uint*)(agg + (size_t)node * HH + lane * 2) = o;
}

// ---------------- fused MLP: out = relu(relu(X@W1+b1)@W2+b2), X=(1+eps)h+agg --------

__global__ __launch_bounds__(256) void fused_mlp(const ushort* __restrict__ xin,
                                                 const ushort* __restrict__ agg,
                                                 const ushort* __restrict__ wt1,  // [n][k]
                                                 const ushort* __restrict__ wt2,  // [n][k]
                                                 const float* __restrict__ b1,
                                                 const float* __restrict__ b2,
                                                 const float* __restrict__ epsp, int layer,
                                                 ushort* __restrict__ out, int nrows) {
    __shared__ __align__(16) ushort xs[64][136];
    __shared__ __align__(16) ushort hs[64][136];
    const int tid = threadIdx.x;
    const int lane = tid & 63, w = tid >> 6;
    const int row0 = blockIdx.x * 64;
    const int l15 = lane & 15, lhi = lane >> 4;

    short8 a1[2][4], a2[2][4];
#pragma unroll
    for (int fa = 0; fa < 2; ++fa)
#pragma unroll
        for (int kt = 0; kt < 4; ++kt) {
            int n = w * 32 + fa * 16 + l15;
            int k = kt * 32 + lhi * 8;
            a1[fa][kt] = *(const short8*)(wt1 + n * HH + k);
            a2[fa][kt] = *(const short8*)(wt2 + n * HH + k);
        }

    float eps1 = 1.0f + epsp[layer];
#pragma unroll
    for (int it = 0; it < 4; ++it) {
        int idx = it * 256 + tid;
        int r = idx >> 4, kq = idx & 15;
        int row = row0 + r;
        uint4 xv = make_uint4(0u, 0u, 0u, 0u);
        if (row < nrows) {
            xv = *(const uint4*)(xin + (size_t)row * HH + kq * 8);
            uint4 av = *(const uint4*)(agg + (size_t)row * HH + kq * 8);
            xv.x = comb2(xv.x, av.x, eps1);
            xv.y = comb2(xv.y, av.y, eps1);
            xv.z = comb2(xv.z, av.z, eps1);
            xv.w = comb2(xv.w, av.w, eps1);
        }
        *(uint4*)&xs[r][kq * 8] = xv;
    }
    __syncthreads();

    f32x4 acc[2][4];
#pragma unroll
    for (int fa = 0; fa < 2; ++fa)
#pragma unroll
        for (int fb = 0; fb < 4; ++fb) acc[fa][fb] = (f32x4)(0.f);
#pragma unroll
    for (int kt = 0; kt < 4; ++kt) {
        short8 bfr[4];
#pragma unroll
        for (int fb = 0; fb < 4; ++fb)
            bfr[fb] = *(const short8*)&xs[fb * 16 + l15][kt * 32 + lhi * 8];
#pragma unroll
        for (int fa = 0; fa < 2; ++fa)
#pragma unroll
            for (int fb = 0; fb < 4; ++fb)
                acc[fa][fb] = __builtin_amdgcn_mfma_f32_16x16x32_bf16(a1[fa][kt], bfr[fb],
                                                                     acc[fa][fb], 0, 0, 0);
    }

#pragma unroll
    for (int fa = 0; fa < 2; ++fa) {
        int nb = w * 32 + fa * 16 + lhi * 4;
        float4 bv = *(const float4*)(b1 + nb);
#pragma unroll
        for (int fb = 0; fb < 4; ++fb) {
            ushort4 o;
            o.x = f2b(fmaxf(acc[fa][fb][0] + bv.x, 0.f));
            o.y = f2b(fmaxf(acc[fa][fb][1] + bv.y, 0.f));
            o.z = f2b(fmaxf(acc[fa][fb][2] + bv.z, 0.f));
            o.w = f2b(fmaxf(acc[fa][fb][3] + bv.w, 0.f));
            *(ushort4*)&hs[fb * 16 + l15][nb] = o;
        }
    }
    __syncthreads();

#pragma unroll
    for (int fa = 0; fa < 2; ++fa)
#pragma unroll
        for (int fb = 0; fb < 4; ++fb) acc[fa][fb] = (f32x4)(0.f);
#pragma unroll
    for (int kt = 0; kt < 4; ++kt) {
        short8 bfr[4];
#pragma unroll
        for (int fb = 0; fb < 4; ++fb)
            bfr[fb] = *(const short8*)&hs[fb * 16 + l15][kt * 32 + lhi * 8];
#pragma unroll
        for (int fa = 0; fa < 2; ++fa)
#pragma unroll
            for (int fb = 0; fb < 4; ++fb)
                acc[fa][fb] = __builtin_amdgcn_mfma_f32_16x16x32_bf16(a2[fa][kt], bfr[fb],
                                                                     acc[fa][fb], 0, 0, 0);
    }

#pragma unroll
    for (int fa = 0; fa < 2; ++fa) {
        int nb = w * 32 + fa * 16 + lhi * 4;
        float4 bv = *(const float4*)(b2 + nb);
#pragma unroll
        for (int fb = 0; fb < 4; ++fb) {
            int m = row0 + fb * 16 + l15;
            if (m < nrows) {
                ushort4 o;
                o.x = f2b(fmaxf(acc[fa][fb][0] + bv.x, 0.f));
                o.y = f2b(fmaxf(acc[fa][fb][1] + bv.y, 0.f));
                o.z = f2b(fmaxf(acc[fa][fb][2] + bv.z, 0.f));
                o.w = f2b(fmaxf(acc[fa][fb][3] + bv.w, 0.f));
                *(ushort4*)(out + (size_t)m * HH + nb) = o;
            }
        }
    }
}

// ---------------- sum pooling: 64 nodes/block, 256 threads, register accumulate ------

__global__ __launch_bounds__(256) void pool_kernel(const ushort* __restrict__ h,
                                                   const int* __restrict__ gid,
                                                   float* hg) {
    int j = threadIdx.x & 63;        // uint col-pair index
    int r0 = threadIdx.x >> 6;       // 0..3
    int n0 = blockIdx.x * 64;
    float ax = 0.f, ay = 0.f;
    int gcur = -1;
#pragma unroll
    for (int i = 0; i < 16; ++i) {
        int n = n0 + r0 + i * 4;
        if (n >= NN) break;
        int g = gid[n];
        if (g != gcur) {
            if (gcur >= 0) {
                atomicAdd(&hg[gcur * HH + 2 * j], ax);
                atomicAdd(&hg[gcur * HH + 2 * j + 1], ay);
            }
            gcur = g; ax = 0.f; ay = 0.f;
        }
        uint v = *(const uint*)(h + (size_t)n * HH + 2 * j);
        ax += lo2f(v); ay += hi2f(v);
    }
    if (gcur >= 0) {
        atomicAdd(&hg[gcur * HH + 2 * j], ax);
        atomicAdd(&hg[gcur * HH + 2 * j + 1], ay);
    }
}

// ---------------- classifier head (fp32) ----------------

__global__ __launch_bounds__(128) void classify_kernel(const float* __restrict__ hg,
                                                       const float* __restrict__ wc1,
                                                       const float* __restrict__ bc1,
                                                       const float* __restrict__ wc2,
                                                       const float* __restrict__ bc2,
                                                       float* __restrict__ out) {
    __shared__ float xrow[HH];
    __shared__ float trow[HH];
    int g = blockIdx.x, j = threadIdx.x;
    xrow[j] = hg[g * HH + j];
    __syncthreads();
    float s = bc1[j];
#pragma unroll 8
    for (int k = 0; k < HH; ++k) s += xrow[k] * wc1[k * HH + j];
    trow[j] = fmaxf(s, 0.f);
    __syncthreads();
    if (j < CC) {
        float o = bc2[j];
#pragma unroll 8
        for (int k = 0; k < HH; ++k) o += trow[k] * wc2[k * CC + j];
        out[g * CC + j] = o;
    }
}

extern "C" void kernel_launch(void* const* d_in, const int* in_sizes, int n_in,
                              void* d_out, int out_size, void* d_ws, size_t ws_size,
                              hipStream_t stream) {
    const float* features = (const float*)d_in[0];
    const int* src = (const int*)d_in[1];
    const int* dst = (const int*)d_in[2];
    const int* gid = (const int*)d_in[3];
    const float* eps = (const float*)d_in[4];
    const float* w1[3] = {(const float*)d_in[5], (const float*)d_in[9], (const float*)d_in[13]};
    const float* b1[3] = {(const float*)d_in[6], (const float*)d_in[10], (const float*)d_in[14]};
    const float* w2[3] = {(const float*)d_in[7], (const float*)d_in[11], (const float*)d_in[15]};
    const float* b2[3] = {(const float*)d_in[8], (const float*)d_in[12], (const float*)d_in[16]};
    const float* wc1 = (const float*)d_in[17];
    const float* bc1 = (const float*)d_in[18];
    const float* wc2 = (const float*)d_in[19];
    const float* bc2 = (const float*)d_in[20];
    float* outp = (float*)d_out;

    char* ws = (char*)d_ws;
    size_t off = 0;
    auto alloc = [&](size_t bytes) {
        void* p = ws + off;
        off += (bytes + 255) & ~(size_t)255;
        return p;
    };
    int* rowptr = (int*)alloc((NN + 1) * sizeof(int));
    int* cursor = (int*)alloc(NN * sizeof(int));
    int* eidx = (int*)alloc(EE * sizeof(int));
    int* bsum = (int*)alloc(128 * sizeof(int));
    ushort* hb0 = (ushort*)alloc((size_t)NN * HH * 2);    // features bf16
    ushort* hb1 = (ushort*)alloc((size_t)NN * HH * 2);    // layer h bf16
    ushort* aggb = (ushort*)alloc((size_t)NN * HH * 2);   // aggregate bf16
    ushort* wtb = (ushort*)alloc(6 * 16384 * 2);          // transposed bf16 weights
    float* hg = (float*)alloc(GG * HH * sizeof(float));

    const int NB = (NN + 511) / 512;  // 98

    // CSR build
    hipMemsetAsync(cursor, 0, NN * sizeof(int), stream);
    count_kernel<<<(EE + 255) / 256, 256, 0, stream>>>(dst, cursor);
    scan1_kernel<<<NB, 512, 0, stream>>>(cursor, bsum);
    scan2_kernel<<<1, 128, 0, stream>>>(bsum, rowptr, NB);
    scan3_kernel<<<NB, 512, 0, stream>>>(cursor, bsum, rowptr, cursor);
    fill_kernel<<<(EE + 255) / 256, 256, 0, stream>>>(src, dst, cursor, eidx);

    // conversions
    f2b_kernel<<<(NN * HH / 4 + 255) / 256, 256, 0, stream>>>(features, hb0, NN * HH / 4);
    dim3 wg(64, 6);
    wconv_kernel<<<wg, 256, 0, stream>>>(w1[0], w2[0], w1[1], w2[1], w1[2], w2[2], wtb);
    // wtb layout: [0]=w1_0, [1]=w2_0, [2]=w1_1, [3]=w2_1, [4]=w1_2, [5]=w2_2

    const int GB = (NN + 63) / 64;  // 782

    // 3 GIN layers (aggregate + fused 2-GEMM MLP)
    const ushort* hin = hb0;
    for (int i = 0; i < 3; ++i) {
        aggregate_kernel<<<(NN + 3) / 4, 256, 0, stream>>>(hin, rowptr, eidx, aggb);
        fused_mlp<<<GB, 256, 0, stream>>>(hin, aggb, wtb + (2 * i) * 16384,
                                          wtb + (2 * i + 1) * 16384,
                                          b1[i], b2[i], eps, i, hb1, NN);
        hin = hb1;
    }

    // pooling + classifier
    hipMemsetAsync(hg, 0, GG * HH * sizeof(float), stream);
    pool_kernel<<<(NN + 63) / 64, 256, 0, stream>>>(hb1, gid, hg);
    classify_kernel<<<GG, 128, 0, stream>>>(hg, wc1, bc1, wc2, bc2, outp);
}